// Round 19
// baseline (560.974 us; speedup 1.0000x reference)
//
#include <hip/hip_runtime.h>
#include <hip/hip_bf16.h>
#include <hip/hip_cooperative_groups.h>

#define N 8192
#define D 256
#define NF 8192.0f

namespace cg = cooperative_groups;

typedef __bf16 bf16x8 __attribute__((ext_vector_type(8)));
typedef float f32x4 __attribute__((ext_vector_type(4)));

static __device__ __forceinline__ unsigned short f2bf(float x) {
    union { float f; unsigned int u; } c; c.f = x;
    unsigned int r = (c.u + 0x7fffu + ((c.u >> 16) & 1u)) >> 16;
    return (unsigned short)r;
}
static __device__ __forceinline__ float bf2f(unsigned short u) {
    union { float f; unsigned int u; } c; c.u = ((unsigned int)u) << 16;
    return c.f;
}

// One cooperative kernel, 6 phases.
// grid 512 x 256 threads (2 blocks/CU co-resident).
__global__ __launch_bounds__(256, 2) void mega_k(const float* __restrict__ o1,
                                                 const float* __restrict__ o2,
                                                 unsigned char* __restrict__ w,
                                                 float* __restrict__ out) {
    // workspace carve (matches host)
    unsigned char*  a_bf = w;                                        // 4 MB
    unsigned char*  bt   = w + (size_t)4 * 1024 * 1024;              // 4 MB
    float*          pM   = (float*)(w + (size_t)8 * 1024 * 1024);    // 4 MB [16][256][256]
    unsigned char*  Mb   = w + (size_t)12 * 1024 * 1024;             // 128 KB bf16[256][256]
    float*          vp   = (float*)(w + (size_t)12 * 1024 * 1024 + 131072); // 512 KB [512][256]
    float*          v    = vp + 512 * 256;                           // 1 KB
    float*          diag = v + 256;                                  // 32 KB
    float*          s1p  = diag + N;                                 // 256 KB
    float*          s2p  = s1p + (size_t)8 * N;                      // 256 KB
    float*          partial = s2p + (size_t)8 * N;                   // 256 B

    cg::grid_group grid = cg::this_grid();

    const int bid = blockIdx.x;            // 0..511
    const int tid = threadIdx.x;           // 0..255
    const int lane = tid & 63, wv = tid >> 6;
    const int l15 = lane & 15, lk = lane >> 4;

    __shared__ unsigned short tile[16][256];   // 8 KB (phase 1)
    __shared__ float sred[8];

    // ================= Phase 1: conv (all 512 blocks, 16 rows each) =================
    {
        const int r0 = bid * 16;
        #pragma unroll
        for (int t = 0; t < 4; ++t) {
            const int jloc = wv * 4 + t;
            const int r = r0 + jloc;
            float4 x1 = ((const float4*)(o1 + (size_t)r * D))[lane];
            float4 x2 = ((const float4*)(o2 + (size_t)r * D))[lane];
            float s1 = x1.x*x1.x + x1.y*x1.y + x1.z*x1.z + x1.w*x1.w;
            float s2 = x2.x*x2.x + x2.y*x2.y + x2.z*x2.z + x2.w*x2.w;
            float sd = x1.x*x2.x + x1.y*x2.y + x1.z*x2.z + x1.w*x2.w;
            #pragma unroll
            for (int m = 1; m < 64; m <<= 1) {
                s1 += __shfl_xor(s1, m);
                s2 += __shfl_xor(s2, m);
                sd += __shfl_xor(sd, m);
            }
            float i1 = 1.0f / sqrtf(s1);
            float i2 = 1.0f / sqrtf(s2);
            if (lane == 0) diag[r] = sd * i1 * i2;

            uint2 qa;
            qa.x = (unsigned int)f2bf(x1.x * i1) | ((unsigned int)f2bf(x1.y * i1) << 16);
            qa.y = (unsigned int)f2bf(x1.z * i1) | ((unsigned int)f2bf(x1.w * i1) << 16);
            *(uint2*)(a_bf + (size_t)r * 512 + lane * 8) = qa;

            uint2 qb;
            qb.x = (unsigned int)f2bf(x2.x * i2) | ((unsigned int)f2bf(x2.y * i2) << 16);
            qb.y = (unsigned int)f2bf(x2.z * i2) | ((unsigned int)f2bf(x2.w * i2) << 16);
            *(uint2*)&tile[jloc][lane * 4] = qb;
        }
        __syncthreads();

        // transpose out: thread k = tid; 16 rows -> 32 B at Bt[k][r0..r0+15]
        const int k = tid;
        float vs = 0.f;
        unsigned int pk[8];
        #pragma unroll
        for (int j = 0; j < 8; ++j) {
            unsigned short y0 = tile[2 * j][k];
            unsigned short y1 = tile[2 * j + 1][k];
            vs += bf2f(y0) + bf2f(y1);
            pk[j] = (unsigned int)y0 | ((unsigned int)y1 << 16);
        }
        uint4* dst = (uint4*)(bt + (size_t)k * (2 * N) + (size_t)r0 * 2);
        uint4 u0; u0.x = pk[0]; u0.y = pk[1]; u0.z = pk[2]; u0.w = pk[3];
        uint4 u1; u1.x = pk[4]; u1.y = pk[5]; u1.z = pk[6]; u1.w = pk[7];
        dst[0] = u0; dst[1] = u1;
        vp[(size_t)bid * 256 + k] = vs;
    }
    __threadfence();
    grid.sync();

    // ===== Phase 2: M partials (blocks 0..63 = 4 row-slabs x 16 K-splits) + v (block 64)
    if (bid < 64) {
        const int slab = bid >> 4, s = bid & 15;
        const int j0 = s * 512;
        const int rA = slab * 64 + wv * 16;

        f32x4 acc[16];
        #pragma unroll
        for (int nt = 0; nt < 16; ++nt) acc[nt] = (f32x4){0.f, 0.f, 0.f, 0.f};

        #pragma unroll 1
        for (int ks = 0; ks < 16; ++ks) {
            const size_t jb = (size_t)(j0 + ks * 32) * 2 + lk * 16;
            bf16x8 afr = *(const bf16x8*)(bt + (size_t)(rA + l15) * (2 * N) + jb);
            #pragma unroll
            for (int nt = 0; nt < 16; ++nt) {
                bf16x8 bfr = *(const bf16x8*)(bt + (size_t)(nt * 16 + l15) * (2 * N) + jb);
                acc[nt] = __builtin_amdgcn_mfma_f32_16x16x32_bf16(afr, bfr, acc[nt], 0, 0, 0);
            }
        }
        #pragma unroll
        for (int nt = 0; nt < 16; ++nt)
            #pragma unroll
            for (int rg = 0; rg < 4; ++rg) {
                int row = rA + lk * 4 + rg;
                int col = nt * 16 + l15;
                pM[((size_t)s * 256 + row) * 256 + col] = acc[nt][rg];
            }
    } else if (bid == 64) {
        const int k = tid;
        float s0 = 0.f, s1 = 0.f, s2 = 0.f, s3 = 0.f;
        #pragma unroll 4
        for (int b = 0; b < 512; b += 4) {
            s0 += vp[(size_t)b * 256 + k];
            s1 += vp[(size_t)(b + 1) * 256 + k];
            s2 += vp[(size_t)(b + 2) * 256 + k];
            s3 += vp[(size_t)(b + 3) * 256 + k];
        }
        v[k] = (s0 + s1) + (s2 + s3);
    }
    __threadfence();
    grid.sync();

    // ================= Phase 3: reduce 16 partials -> Mb bf16 (blocks 0..255) ========
    if (bid < 256) {
        const int i = bid * 256 + tid;
        float s = 0.f;
        #pragma unroll
        for (int s16 = 0; s16 < 16; ++s16) s += pM[(size_t)s16 * (D * D) + i];
        ((unsigned short*)Mb)[i] = f2bf(s);
    }
    __threadfence();
    grid.sync();

    // ================= Phase 4: quadratic forms (all 512 blocks = 64 rq x 8 ne) ======
    {
        const int rq = bid >> 3, ne = bid & 7;
        const int rowbase = rq * 128 + wv * 32;

        bf16x8 af[2][8];
        #pragma unroll
        for (int mr = 0; mr < 2; ++mr)
            #pragma unroll
            for (int ks = 0; ks < 8; ++ks)
                af[mr][ks] = *(const bf16x8*)(a_bf + (size_t)(rowbase + mr * 16 + l15) * 512
                                                   + ks * 64 + lk * 16);

        f32x4 acc[2][2];
        #pragma unroll
        for (int mr = 0; mr < 2; ++mr)
            #pragma unroll
            for (int nt = 0; nt < 2; ++nt)
                acc[mr][nt] = (f32x4){0.f, 0.f, 0.f, 0.f};

        #pragma unroll
        for (int ks = 0; ks < 8; ++ks) {
            bf16x8 bfr[2];
            #pragma unroll
            for (int nt = 0; nt < 2; ++nt) {
                int n = ne * 32 + nt * 16 + l15;
                bfr[nt] = *(const bf16x8*)(Mb + (size_t)n * 512 + ks * 64 + lk * 16);
            }
            #pragma unroll
            for (int mr = 0; mr < 2; ++mr)
                #pragma unroll
                for (int nt = 0; nt < 2; ++nt)
                    acc[mr][nt] = __builtin_amdgcn_mfma_f32_16x16x32_bf16(
                        af[mr][ks], bfr[nt], acc[mr][nt], 0, 0, 0);
        }

        const float v0 = v[ne * 32 + l15];
        const float v1 = v[ne * 32 + 16 + l15];
        #pragma unroll
        for (int mr = 0; mr < 2; ++mr)
            #pragma unroll
            for (int rg = 0; rg < 4; ++rg) {
                const int row = rowbase + mr * 16 + lk * 4 + rg;
                float a0 = bf2f(*(const unsigned short*)(a_bf + (size_t)row * 512
                                                         + (ne * 32 + l15) * 2));
                float a1 = bf2f(*(const unsigned short*)(a_bf + (size_t)row * 512
                                                         + (ne * 32 + 16 + l15) * 2));
                float s2v = acc[mr][0][rg] * a0 + acc[mr][1][rg] * a1;
                float s1v = a0 * v0 + a1 * v1;
                #pragma unroll
                for (int m = 1; m < 16; m <<= 1) {
                    s2v += __shfl_xor(s2v, m);
                    s1v += __shfl_xor(s1v, m);
                }
                if (l15 == 0) {
                    s2p[(size_t)ne * N + row] = s2v;
                    s1p[(size_t)ne * N + row] = s1v;
                }
            }
    }
    __threadfence();
    grid.sync();

    // ================= Phase 5: per-row loss + block reduce (blocks 0..63) ===========
    if (bid < 64) {
        float lossacc = 0.f;
        if (tid < 128) {
            const int row = bid * 128 + tid;
            float s1 = 0.f, s2 = 0.f;
            #pragma unroll
            for (int ne = 0; ne < 8; ++ne) {
                s1 += s1p[(size_t)ne * N + row];
                s2 += s2p[(size_t)ne * N + row];
            }
            lossacc = logf(NF + s1 + 0.5f * s2) - diag[row];
        }
        #pragma unroll
        for (int m = 1; m < 64; m <<= 1) lossacc += __shfl_xor(lossacc, m);
        if (lane == 0) sred[wv] = lossacc;
        __syncthreads();
        if (tid == 0) partial[bid] = sred[0] + sred[1] + sred[2] + sred[3];
    }
    __threadfence();
    grid.sync();

    // ================= Phase 6: final mean (block 0) =================================
    if (bid == 0 && tid < 64) {
        float x = partial[tid];
        #pragma unroll
        for (int m = 1; m < 64; m <<= 1) x += __shfl_xor(x, m);
        if (tid == 0) out[0] = x / NF;
    }
}

extern "C" void kernel_launch(void* const* d_in, const int* in_sizes, int n_in,
                              void* d_out, int out_size, void* d_ws, size_t ws_size,
                              hipStream_t stream) {
    const float* o1 = (const float*)d_in[0];
    const float* o2 = (const float*)d_in[1];
    unsigned char* w = (unsigned char*)d_ws;
    float* outp = (float*)d_out;

    void* args[] = { (void*)&o1, (void*)&o2, (void*)&w, (void*)&outp };
    hipLaunchCooperativeKernel((void*)mega_k, dim3(512), dim3(256), args, 0, stream);
}

// Round 20
// 57.345 us; speedup vs baseline: 9.7825x; 9.7825x over previous
//
#include <hip/hip_runtime.h>
#include <hip/hip_bf16.h>

#define N 8192
#define D 256
#define NF 8192.0f

typedef __bf16 bf16x8 __attribute__((ext_vector_type(8)));
typedef float f32x4 __attribute__((ext_vector_type(4)));

static __device__ __forceinline__ unsigned short f2bf(float x) {
    union { float f; unsigned int u; } c; c.f = x;
    unsigned int r = (c.u + 0x7fffu + ((c.u >> 16) & 1u)) >> 16;
    return (unsigned short)r;
}
static __device__ __forceinline__ float bf2f(unsigned short u) {
    union { float f; unsigned int u; } c; c.u = ((unsigned int)u) << 16;
    return c.f;
}
static __device__ __forceinline__ void gll16(const void* g, void* l) {
    __builtin_amdgcn_global_load_lds(
        (const __attribute__((address_space(1))) void*)g,
        (__attribute__((address_space(3))) void*)l, 16, 0, 0);
}

// ---------- kernel 1 (grid 512): norms, fp32 diag, A-hat bf16 XOR-swizzled,
// ----------  Bt = B-hat^T bf16 [256][8192] via LDS transpose (16 rows/block) ----------
__global__ __launch_bounds__(256) void conv_k(const float* __restrict__ o1,
                                              const float* __restrict__ o2,
                                              unsigned char* __restrict__ a_bf,
                                              unsigned char* __restrict__ bt,
                                              float* __restrict__ diag) {
    __shared__ unsigned short tile[16][256];   // 8 KB
    const int wv = threadIdx.x >> 6, lane = threadIdx.x & 63;
    const int r0 = blockIdx.x * 16;

    #pragma unroll
    for (int t = 0; t < 4; ++t) {
        const int jloc = wv * 4 + t;
        const int r = r0 + jloc;
        float4 x1 = ((const float4*)(o1 + (size_t)r * D))[lane];
        float4 x2 = ((const float4*)(o2 + (size_t)r * D))[lane];
        float s1 = x1.x*x1.x + x1.y*x1.y + x1.z*x1.z + x1.w*x1.w;
        float s2 = x2.x*x2.x + x2.y*x2.y + x2.z*x2.z + x2.w*x2.w;
        float sd = x1.x*x2.x + x1.y*x2.y + x1.z*x2.z + x1.w*x2.w;
        #pragma unroll
        for (int m = 1; m < 64; m <<= 1) {
            s1 += __shfl_xor(s1, m);
            s2 += __shfl_xor(s2, m);
            sd += __shfl_xor(sd, m);
        }
        float i1 = 1.0f / sqrtf(s1);
        float i2 = 1.0f / sqrtf(s2);
        if (lane == 0) diag[r] = sd * i1 * i2;

        // A-hat, XOR-pre-swizzled: chunk (lane>>1) stored at chunk ^ (r & 31)
        {
            uint2 qa;
            qa.x = (unsigned int)f2bf(x1.x * i1) | ((unsigned int)f2bf(x1.y * i1) << 16);
            qa.y = (unsigned int)f2bf(x1.z * i1) | ((unsigned int)f2bf(x1.w * i1) << 16);
            int cs = (lane >> 1) ^ (r & 31);
            *(uint2*)(a_bf + (size_t)r * 512 + cs * 16 + (lane & 1) * 8) = qa;
        }
        // B-hat row -> LDS tile
        {
            uint2 qb;
            qb.x = (unsigned int)f2bf(x2.x * i2) | ((unsigned int)f2bf(x2.y * i2) << 16);
            qb.y = (unsigned int)f2bf(x2.z * i2) | ((unsigned int)f2bf(x2.w * i2) << 16);
            *(uint2*)&tile[jloc][lane * 4] = qb;
        }
    }
    __syncthreads();

    // transpose out: thread k = tid; 16 rows -> 32 B at Bt[k][r0..r0+15]
    const int k = threadIdx.x;
    unsigned int pk[8];
    #pragma unroll
    for (int j = 0; j < 8; ++j) {
        unsigned short y0 = tile[2 * j][k];
        unsigned short y1 = tile[2 * j + 1][k];
        pk[j] = (unsigned int)y0 | ((unsigned int)y1 << 16);
    }
    uint4* dst = (uint4*)(bt + (size_t)k * (2 * N) + (size_t)r0 * 2);
    uint4 u0; u0.x = pk[0]; u0.y = pk[1]; u0.z = pk[2]; u0.w = pk[3];
    uint4 u1; u1.x = pk[4]; u1.y = pk[5]; u1.z = pk[6]; u1.w = pk[7];
    dst[0] = u0; dst[1] = u1;
}

// ---------- kernel 2 (grid 32): M partials over j-windows of 256 (r17, proven) ------
__global__ __launch_bounds__(512) void mker(const unsigned char* __restrict__ bt,
                                            float* __restrict__ pM) {
    const int tid = threadIdx.x, lane = tid & 63, wid = tid >> 6;
    const int wm = wid & 1, wn = wid >> 1;
    const int l15 = lane & 15, lk = lane >> 4;
    const int j0 = blockIdx.x * 256;

    f32x4 acc[8][4];
    #pragma unroll
    for (int mt = 0; mt < 8; ++mt)
        #pragma unroll
        for (int nt = 0; nt < 4; ++nt)
            acc[mt][nt] = (f32x4){0.f, 0.f, 0.f, 0.f};

    #pragma unroll
    for (int ks = 0; ks < 8; ++ks) {
        const size_t joff = (size_t)(j0 + ks * 32) * 2 + lk * 16;
        bf16x8 afr[8], bfr[4];
        #pragma unroll
        for (int mt = 0; mt < 8; ++mt)
            afr[mt] = *(const bf16x8*)(bt + (size_t)(wm * 128 + mt * 16 + l15) * (2 * N) + joff);
        #pragma unroll
        for (int nt = 0; nt < 4; ++nt)
            bfr[nt] = *(const bf16x8*)(bt + (size_t)(wn * 64 + nt * 16 + l15) * (2 * N) + joff);
        #pragma unroll
        for (int mt = 0; mt < 8; ++mt)
            #pragma unroll
            for (int nt = 0; nt < 4; ++nt)
                acc[mt][nt] = __builtin_amdgcn_mfma_f32_16x16x32_bf16(
                    afr[mt], bfr[nt], acc[mt][nt], 0, 0, 0);
    }

    float* out = pM + (size_t)blockIdx.x * (D * D);
    #pragma unroll
    for (int mt = 0; mt < 8; ++mt)
        #pragma unroll
        for (int nt = 0; nt < 4; ++nt)
            #pragma unroll
            for (int rg = 0; rg < 4; ++rg) {
                int row = wm * 128 + mt * 16 + lk * 4 + rg;
                int col = wn * 64 + nt * 16 + l15;
                out[row * D + col] = acc[mt][nt][rg];
            }
}

// ---------- kernel 3 (grid 128): reduce partials -> Mb bf16 AND v = Bt row-sums ------
__global__ __launch_bounds__(512) void redcvt(const float* __restrict__ pM,
                                              const unsigned char* __restrict__ bt,
                                              unsigned short* __restrict__ Mb,
                                              float* __restrict__ v) {
    const int i = blockIdx.x * 512 + threadIdx.x;   // 0..65535
    float s = 0.f;
    #pragma unroll
    for (int b = 0; b < 32; ++b) s += pM[(size_t)b * (D * D) + i];
    Mb[i] = f2bf(s);

    const int lane = threadIdx.x & 63, wid = threadIdx.x >> 6;
    const int half = threadIdx.x >> 8;
    const int t255 = threadIdx.x & 255;
    const int row = blockIdx.x * 2 + half;
    const uint4* sp = (const uint4*)(bt + (size_t)row * (2 * N) + t255 * 64);
    float vs = 0.f;
    #pragma unroll
    for (int q = 0; q < 4; ++q) {
        uint4 u = sp[q];
        unsigned int ww[4] = {u.x, u.y, u.z, u.w};
        #pragma unroll
        for (int e = 0; e < 4; ++e) {
            vs += bf2f((unsigned short)(ww[e] & 0xffffu));
            vs += bf2f((unsigned short)(ww[e] >> 16));
        }
    }
    #pragma unroll
    for (int m = 1; m < 64; m <<= 1) vs += __shfl_xor(vs, m);
    __shared__ float vred[8];
    if (lane == 0) vred[wid] = vs;
    __syncthreads();
    if (threadIdx.x == 0)   v[row] = vred[0] + vred[1] + vred[2] + vred[3];
    if (threadIdx.x == 256) v[row] = vred[4] + vred[5] + vred[6] + vred[7];
}

// ---------- kernel 4 (grid 256): quadratic forms + per-row loss, LDS-staged A --------
// block: 32 rows x all 256 cols; 4 waves = 2 row-halves x 2 ne-halves.
__global__ __launch_bounds__(256) void qfrow(const unsigned char* __restrict__ a_bf,
                                             const unsigned char* __restrict__ Mb,
                                             const float* __restrict__ v,
                                             const float* __restrict__ diag,
                                             float* __restrict__ partial) {
    __shared__ __align__(16) unsigned char As[32 * 512];   // 16 KB swizzled bf16
    __shared__ float vs[256];
    __shared__ float s1h[2][32], s2h[2][32];

    const int tid = threadIdx.x, lane = tid & 63, wid = tid >> 6;
    const int wr = wid & 1, wh = wid >> 1;
    const int l15 = lane & 15, lk = lane >> 4;
    const int R0 = blockIdx.x * 32;

    #pragma unroll
    for (int it = 0; it < 4; ++it) {
        int x = it * 4096 + tid * 16;
        gll16(a_bf + (size_t)R0 * 512 + x, As + x);
    }
    vs[tid] = v[tid];
    asm volatile("s_waitcnt vmcnt(0)" ::: "memory");
    __syncthreads();

    // af frags from swizzled LDS (conflict-free)
    const int row_l = wr * 16 + l15;
    bf16x8 af[8];
    #pragma unroll
    for (int ks = 0; ks < 8; ++ks)
        af[ks] = *(const bf16x8*)(As + row_l * 512 + (((ks * 4 + lk) ^ row_l) * 16));

    float s1v[4], s2v[4];
    #pragma unroll
    for (int rg = 0; rg < 4; ++rg) { s1v[rg] = 0.f; s2v[rg] = 0.f; }

    #pragma unroll
    for (int nei = 0; nei < 4; ++nei) {
        const int ne = wh * 4 + nei;
        f32x4 acc0 = (f32x4){0.f, 0.f, 0.f, 0.f};
        f32x4 acc1 = (f32x4){0.f, 0.f, 0.f, 0.f};
        const int n0 = ne * 32 + l15, n1 = ne * 32 + 16 + l15;
        #pragma unroll
        for (int ks = 0; ks < 8; ++ks) {
            bf16x8 b0 = *(const bf16x8*)(Mb + (size_t)n0 * 512 + ks * 64 + lk * 16);
            bf16x8 b1 = *(const bf16x8*)(Mb + (size_t)n1 * 512 + ks * 64 + lk * 16);
            acc0 = __builtin_amdgcn_mfma_f32_16x16x32_bf16(af[ks], b0, acc0, 0, 0, 0);
            acc1 = __builtin_amdgcn_mfma_f32_16x16x32_bf16(af[ks], b1, acc1, 0, 0, 0);
        }
        #pragma unroll
        for (int rg = 0; rg < 4; ++rg) {
            const int rl = wr * 16 + lk * 4 + rg;
            const int c0 = ne * 32 + l15, c1 = ne * 32 + 16 + l15;
            float a0 = bf2f(*(const unsigned short*)(As + rl * 512
                            + (((c0 >> 3) ^ rl) * 16) + (c0 & 7) * 2));
            float a1 = bf2f(*(const unsigned short*)(As + rl * 512
                            + (((c1 >> 3) ^ rl) * 16) + (c1 & 7) * 2));
            s2v[rg] += acc0[rg] * a0 + acc1[rg] * a1;
            s1v[rg] += a0 * vs[c0] + a1 * vs[c1];
        }
    }

    // reduce across the 16 column-lanes
    #pragma unroll
    for (int rg = 0; rg < 4; ++rg) {
        #pragma unroll
        for (int m = 1; m < 16; m <<= 1) {
            s1v[rg] += __shfl_xor(s1v[rg], m);
            s2v[rg] += __shfl_xor(s2v[rg], m);
        }
    }
    if (l15 == 0) {
        #pragma unroll
        for (int rg = 0; rg < 4; ++rg) {
            const int rl = wr * 16 + lk * 4 + rg;
            s1h[wh][rl] = s1v[rg];
            s2h[wh][rl] = s2v[rg];
        }
    }
    __syncthreads();
    if (tid < 32) {
        float s1 = s1h[0][tid] + s1h[1][tid];
        float s2 = s2h[0][tid] + s2h[1][tid];
        float loss = logf(NF + s1 + 0.5f * s2) - diag[R0 + tid];
        #pragma unroll
        for (int m = 1; m < 32; m <<= 1) loss += __shfl_xor(loss, m);
        if (tid == 0) partial[blockIdx.x] = loss;
    }
}

// ---------- kernel 5: final mean over 256 partials ----------
__global__ __launch_bounds__(64) void final_k(const float* __restrict__ partial,
                                              float* __restrict__ out) {
    const int t = threadIdx.x;
    float x = partial[t] + partial[t + 64] + partial[t + 128] + partial[t + 192];
    #pragma unroll
    for (int m = 1; m < 64; m <<= 1) x += __shfl_xor(x, m);
    if (t == 0) out[0] = x / NF;
}

extern "C" void kernel_launch(void* const* d_in, const int* in_sizes, int n_in,
                              void* d_out, int out_size, void* d_ws, size_t ws_size,
                              hipStream_t stream) {
    const float* o1 = (const float*)d_in[0];
    const float* o2 = (const float*)d_in[1];

    unsigned char* w = (unsigned char*)d_ws;
    unsigned char*  a_bf = w;                                        // 4 MB
    unsigned char*  bt   = w + (size_t)4 * 1024 * 1024;              // 4 MB
    float*          pM   = (float*)(w + (size_t)8 * 1024 * 1024);    // 8 MB
    unsigned short* Mb   = (unsigned short*)(w + (size_t)16 * 1024 * 1024); // 128 KB
    float*          v    = (float*)(w + (size_t)16 * 1024 * 1024 + 131072); // 1 KB
    float*          diag = v + 256;                                  // 32 KB
    float*          partial = diag + N;                              // 1 KB

    conv_k <<<512, 256, 0, stream>>>(o1, o2, a_bf, bt, diag);
    mker   <<<32, 512, 0, stream>>>(bt, pM);
    redcvt <<<128, 512, 0, stream>>>(pM, bt, Mb, v);
    qfrow  <<<256, 256, 0, stream>>>(a_bf, (const unsigned char*)Mb, v, diag, partial);
    final_k<<<1, 64, 0, stream>>>(partial, (float*)d_out);
}